// Round 7
// baseline (145.876 us; speedup 1.0000x reference)
//
#include <hip/hip_runtime.h>
#include <math.h>

// HOG-3D: central differences -> (theta,phi) soft-binned histogram scatter.
// Output (1,8,8,78,78,78) fp32 = 121.5 MB.
//
// R6 = R5 with the compile fix: __builtin_nontemporal_store requires a NATIVE
// vector type, not HIP's float4 class -> use ext_vector_type(4).
//
// R5 design: single kernel, ZERO auxiliary reads in the store path.
// Evidence R2-R4: dur_us invariant at ~131-132 = harness poison fill (73 us,
// in-window, 486 MB @ 6.6 TB/s) + ~58 us ours, across three different write
// structures. R4's fill-shaped writer still read 243 MB of records through
// the same L2s its writes stream through (loads share the in-order vmcnt
// queue with stores). Fix: no record array -- each thread re-runs the cheap
// analysis (x = 1 MB, cache-resident) for its 4 voxels and writes an 8-plane
// group: 8 contiguous-per-wave 16B nontemporal stores, nothing else.
// Redundancy: 8x analyze ~= 10 us of VALU, hidden under the 19 us write floor.
// Numerics identical to the PASSING R2/R3 chain (f32 numpy-ordered ops,
// CR-f32-via-f64 libm fallback within 1e-4 of a bin boundary).

#define DVOL 64
#define S 78               // 64 + 2*8 - 2
#define S3 (S * S * S)     // 474552
#define NQ (S3 / 4)        // 118638 float4-quads per plane (exact)

typedef float f32x4 __attribute__((ext_vector_type(4)));

__device__ __forceinline__ float ldx(const float* __restrict__ x, int z, int y, int xx) {
    if ((unsigned)z < (unsigned)DVOL && (unsigned)y < (unsigned)DVOL && (unsigned)xx < (unsigned)DVOL)
        return x[(z * DVOL + y) * DVOL + xx];
    return 0.0f;
}

// Analysis chain -- bit-identical to the R2/R3 passing kernels at the binning
// decision (f32 ops in numpy order, CR-f32 libm fallback near boundaries).
__device__ __forceinline__ void analyze(const float* __restrict__ x, int idx,
                                        int& i0, int& i1, int& i2, int& i3,
                                        float& w0, float& w1, float& w2) {
#pragma clang fp contract(off)
    int ox = idx % S;
    int r  = idx / S;
    int oy = r % S;
    int oz = r / S;
    int ix = ox - 7, iy = oy - 7, iz = oz - 7;

    float gz = ldx(x, iz + 1, iy, ix) - ldx(x, iz - 1, iy, ix);
    float gy = ldx(x, iz, iy + 1, ix) - ldx(x, iz, iy - 1, ix);
    float gx = ldx(x, iz, iy, ix + 1) - ldx(x, iz, iy, ix - 1);

    float mag2 = (gz * gz + gy * gy) + gx * gx;   // ((z^2+y^2)+x^2), no FMA
    float mag  = sqrtf(mag2);

    i0 = i1 = i2 = i3 = 0;
    w0 = w1 = w2 = 0.0f;
    if (mag == 0.0f) return;   // zero deposit (adds +0.0f to plane 0 -> exact)

    const float EPS32 = 2.220446049250313e-16f;   // 2^-52, exact in f32
    const float PI32  = 3.14159274101257324f;     // (float)math.pi
    float denom = mag + EPS32;
    float ratio = gz / denom;

    // fast path: device f32 libm (<=2 ulp); CR-f32-via-f64 fallback only when
    // within 1e-4 of an integer bin boundary (~4e-4 of voxels)
    float theta = atan2f(gy, gx);
    float phi   = acosf(ratio);
    float t_raw = theta / PI32 * 8.0f;
    float p_raw = phi   / PI32 * 8.0f;

    float td = fabsf(t_raw - rintf(t_raw));
    float pd = fabsf(p_raw - rintf(p_raw));
    if (td < 1e-4f || pd < 1e-4f) {
        theta = (float)atan2((double)gy, (double)gx);
        phi   = (float)acos((double)ratio);
        t_raw = theta / PI32 * 8.0f;
        p_raw = phi   / PI32 * 8.0f;
    }

    float t_frac = t_raw - truncf(t_raw);         // torch.frac (signed)
    float p_frac = p_raw - truncf(p_raw);

    i0 = ((int)floorf(t_raw)) & 7;                // numpy floored-mod (pow2)
    i1 = ((int)ceilf (t_raw)) & 7;
    i2 = ((int)floorf(p_raw)) & 7;
    i3 = ((int)ceilf (p_raw)) & 7;

    float f0 = fabsf(t_frac), f1 = fabsf(1.0f - t_frac);
    float f2 = fabsf(p_frac), f3 = fabsf(1.0f - p_frac);
    w0 = (f0 * f2) * mag;   // -> (i0, i2)
    w1 = (f0 * f3) * mag;   // -> (i0, i3)
    w2 = (f1 * f2) * mag;   // -> (i1, i2)
}

// One thread: quad q (voxels 4q..4q+3), plane group blockIdx.y (8 planes).
// Per wave, each of the 8 stores is 1 KB contiguous; no loads besides x.
__global__ void __launch_bounds__(256) hog8(const float* __restrict__ x,
                                            f32x4* __restrict__ out4) {
    int q = blockIdx.x * 256 + threadIdx.x;
    if (q >= NQ) return;
    int pg = blockIdx.y * 8;                  // first plane of this group
    int base = q * 4;

    int bb[4][3]; float ww[4][3];
    #pragma unroll
    for (int v = 0; v < 4; ++v) {
        int i0, i1, i2, i3; float w0, w1, w2;
        analyze(x, base + v, i0, i1, i2, i3, w0, w1, w2);
        bb[v][0] = (i0 << 3) | i2;            // b0
        bb[v][1] = (i0 << 3) | i3;            // b1
        bb[v][2] = (i1 << 3) | i2;            // b2
        ww[v][0] = w0; ww[v][1] = w1; ww[v][2] = w2;
    }

    #pragma unroll
    for (int d = 0; d < 8; ++d) {
        int p = pg + d;
        f32x4 val;
        #pragma unroll
        for (int v = 0; v < 4; ++v) {
            // additive fold == reference scatter chain order ((w0+w1)+w2),
            // handles every bin-collision case; +0.0f exact elsewhere
            float s = (bb[v][0] == p ? ww[v][0] : 0.0f);
            s = s + (bb[v][1] == p ? ww[v][1] : 0.0f);
            s = s + (bb[v][2] == p ? ww[v][2] : 0.0f);
            val[v] = s;
        }
        // write-once stream: nontemporal keeps x resident in L2
        __builtin_nontemporal_store(val, &out4[(size_t)p * NQ + q]);
    }
}

extern "C" void kernel_launch(void* const* d_in, const int* in_sizes, int n_in,
                              void* d_out, int out_size, void* d_ws, size_t ws_size,
                              hipStream_t stream) {
    const float* x = (const float*)d_in[0];   // (64,64,64) fp32
    // d_in[1] (sobel weight) is a fixed constant per the reference -- folded in.
    f32x4* out4 = (f32x4*)d_out;

    // grid: 464 chunks x 8 plane-groups = 3712 blocks (~14.5/CU)
    hog8<<<dim3((NQ + 255) / 256, 8), 256, 0, stream>>>(x, out4);
}

// Round 8
// 133.832 us; speedup vs baseline: 1.0900x; 1.0900x over previous
//
#include <hip/hip_runtime.h>
#include <math.h>

// HOG-3D: central differences -> (theta,phi) soft-binned histogram scatter.
// Output (1,8,8,78,78,78) fp32 = 121.5 MB. Write roofline ~19 us @ 6.3 TB/s.
//
// R7: write-footprint clustering. Evidence R2-R6: ours invariant ~58 us
// (=121.5 MB @ ~2.1 TB/s) across dword/float4/record-fed store structures,
// while the harness fill hits 6.5 TB/s in the same runs; NT stores regressed
// (-> keep plain stores). Untried lever: R2/R3 keep ~130k scattered 1 KB
// store chunks in flight (2048 waves x 64 plane-streams each). Here:
//  - thread t owns quad t of a contiguous 256-quad block slab -> per plane,
//    each block writes ONE contiguous 4 KB span (1 KB/wave float4 stores);
//  - raw s_barrier per plane (no data deps -> no vmcnt drain) keeps the
//    block's waves sweeping planes in lockstep; all blocks sweep p=0..63 in
//    the same order -> writes traverse the output like 64 sequential 1.9 MB
//    fills instead of 131k interleaved chunks.
// Analysis runs ONCE per voxel, state in ~16 VGPRs; no LDS, no d_ws, no
// redundancy. Numerics identical to the PASSING R2/R3 chain.

#define DVOL 64
#define S 78               // 64 + 2*8 - 2
#define S3 (S * S * S)     // 474552
#define NQ (S3 / 4)        // 118638 float4-quads per plane (exact)

typedef float f32x4 __attribute__((ext_vector_type(4)));

__device__ __forceinline__ float ldx(const float* __restrict__ x, int z, int y, int xx) {
    if ((unsigned)z < (unsigned)DVOL && (unsigned)y < (unsigned)DVOL && (unsigned)xx < (unsigned)DVOL)
        return x[(z * DVOL + y) * DVOL + xx];
    return 0.0f;
}

// Analysis chain -- bit-identical to the R2/R3 passing kernels at the binning
// decision (f32 ops in numpy order, CR-f32-via-f64 libm fallback within 1e-4
// of an integer bin boundary).
__device__ __forceinline__ void analyze(const float* __restrict__ x, int idx,
                                        int& i0, int& i1, int& i2, int& i3,
                                        float& w0, float& w1, float& w2) {
#pragma clang fp contract(off)
    int ox = idx % S;
    int r  = idx / S;
    int oy = r % S;
    int oz = r / S;
    int ix = ox - 7, iy = oy - 7, iz = oz - 7;

    float gz = ldx(x, iz + 1, iy, ix) - ldx(x, iz - 1, iy, ix);
    float gy = ldx(x, iz, iy + 1, ix) - ldx(x, iz, iy - 1, ix);
    float gx = ldx(x, iz, iy, ix + 1) - ldx(x, iz, iy, ix - 1);

    float mag2 = (gz * gz + gy * gy) + gx * gx;   // ((z^2+y^2)+x^2), no FMA
    float mag  = sqrtf(mag2);

    i0 = i1 = i2 = i3 = 0;
    w0 = w1 = w2 = 0.0f;
    if (mag == 0.0f) return;   // zero deposit everywhere -> exact

    const float EPS32 = 2.220446049250313e-16f;   // 2^-52, exact in f32
    const float PI32  = 3.14159274101257324f;     // (float)math.pi
    float denom = mag + EPS32;
    float ratio = gz / denom;

    float theta = atan2f(gy, gx);
    float phi   = acosf(ratio);
    float t_raw = theta / PI32 * 8.0f;
    float p_raw = phi   / PI32 * 8.0f;

    float td = fabsf(t_raw - rintf(t_raw));
    float pd = fabsf(p_raw - rintf(p_raw));
    if (td < 1e-4f || pd < 1e-4f) {
        theta = (float)atan2((double)gy, (double)gx);
        phi   = (float)acos((double)ratio);
        t_raw = theta / PI32 * 8.0f;
        p_raw = phi   / PI32 * 8.0f;
    }

    float t_frac = t_raw - truncf(t_raw);         // torch.frac (signed)
    float p_frac = p_raw - truncf(p_raw);

    i0 = ((int)floorf(t_raw)) & 7;                // numpy floored-mod (pow2)
    i1 = ((int)ceilf (t_raw)) & 7;
    i2 = ((int)floorf(p_raw)) & 7;
    i3 = ((int)ceilf (p_raw)) & 7;

    float f0 = fabsf(t_frac), f1 = fabsf(1.0f - t_frac);
    float f2 = fabsf(p_frac), f3 = fabsf(1.0f - p_frac);
    w0 = (f0 * f2) * mag;   // -> (i0, i2)
    w1 = (f0 * f3) * mag;   // -> (i0, i3)
    w2 = (f1 * f2) * mag;   // -> (i1, i2)
}

__global__ void __launch_bounds__(256) hog_sweep(const float* __restrict__ x,
                                                 f32x4* __restrict__ out4) {
    int q = blockIdx.x * 256 + threadIdx.x;   // this thread's quad (column)
    bool valid = (q < NQ);
    int base = q * 4;

    // one-time analysis of the 4 voxels of this quad; state lives in VGPRs
    int   bb[4][3];
    float ww[4][3];
    if (valid) {
        #pragma unroll
        for (int v = 0; v < 4; ++v) {
            int i0, i1, i2, i3; float w0, w1, w2;
            analyze(x, base + v, i0, i1, i2, i3, w0, w1, w2);
            bb[v][0] = (i0 << 3) | i2;            // b0
            bb[v][1] = (i0 << 3) | i3;            // b1
            bb[v][2] = (i1 << 3) | i2;            // b2
            ww[v][0] = w0; ww[v][1] = w1; ww[v][2] = w2;
        }
    } else {
        #pragma unroll
        for (int v = 0; v < 4; ++v) {
            bb[v][0] = bb[v][1] = bb[v][2] = -1;
            ww[v][0] = ww[v][1] = ww[v][2] = 0.0f;
        }
    }

    // plane sweep: all blocks traverse p = 0..63 in the same order; the raw
    // s_barrier (no LDS/data deps -> no forced vmcnt drain) keeps this
    // block's 4 waves on the same plane, so each block emits one contiguous
    // 4 KB span per plane and the device sweeps the output plane-by-plane.
    for (int p = 0; p < 64; ++p) {
        if (valid) {
            f32x4 val;
            #pragma unroll
            for (int v = 0; v < 4; ++v) {
                // additive fold == reference scatter chain ((w0+w1)+w2);
                // exact for every bin-collision case; +0.0f elsewhere
                float s = (bb[v][0] == p ? ww[v][0] : 0.0f);
                s = s + (bb[v][1] == p ? ww[v][1] : 0.0f);
                s = s + (bb[v][2] == p ? ww[v][2] : 0.0f);
                val[v] = s;
            }
            out4[(size_t)p * NQ + q] = val;
        }
        __builtin_amdgcn_s_barrier();
    }
}

extern "C" void kernel_launch(void* const* d_in, const int* in_sizes, int n_in,
                              void* d_out, int out_size, void* d_ws, size_t ws_size,
                              hipStream_t stream) {
    const float* x = (const float*)d_in[0];   // (64,64,64) fp32
    // d_in[1] (sobel weight) is a fixed constant per the reference -- folded in.
    f32x4* out4 = (f32x4*)d_out;

    // 464 blocks x 256 threads: block slab = 256 contiguous quads (4 KB/plane)
    hog_sweep<<<(NQ + 255) / 256, 256, 0, stream>>>(x, out4);
}